// Round 8
// baseline (1714.728 us; speedup 1.0000x reference)
//
#include <hip/hip_runtime.h>

#define D 360
#define NAG 64
#define NB 60
#define NPAN 6
#define COV_OFF (NAG * D)
#define INIT_OFF (COV_OFF + NAG * D * D)
// ping-pong R stash in d_ws: [parity][agent][ct][60][60]
#define RBOFF(par, ag, ct) ((((par) * NAG + (ag)) * 6 + (ct)) * 3600)
#define SYNC_OFF 2800000          // float index of the 2 sync words (after 2.76M stash)
#define NWG 256                   // 64 agents x 4 WGs; 1 WG/CU -> co-resident

__device__ __forceinline__ int gshift(int i) {
    return ((i % 60) < 58) ? (i + 2) : i;
}

// ---------------- device-scope grid barrier (generation-based) --------------
__device__ __forceinline__ void gridsync(unsigned* cnt, unsigned* gen) {
    __syncthreads();
    if (threadIdx.x == 0) {
        __threadfence();
        unsigned g = __hip_atomic_load(gen, __ATOMIC_RELAXED, __HIP_MEMORY_SCOPE_AGENT);
        unsigned a = __hip_atomic_fetch_add(cnt, 1u, __ATOMIC_ACQ_REL, __HIP_MEMORY_SCOPE_AGENT);
        if (a == NWG - 1) {
            __hip_atomic_store(cnt, 0u, __ATOMIC_RELAXED, __HIP_MEMORY_SCOPE_AGENT);
            __hip_atomic_fetch_add(gen, 1u, __ATOMIC_RELEASE, __HIP_MEMORY_SCOPE_AGENT);
        } else {
            while (__hip_atomic_load(gen, __ATOMIC_ACQUIRE, __HIP_MEMORY_SCOPE_AGENT) == g)
                __builtin_amdgcn_s_sleep(2);
        }
        __threadfence();
    }
    __syncthreads();
}

// ---------------- 4x4 in-place GJ inverse (no pivoting; SPD blocks) ----------
__device__ __forceinline__ void inv4(float4& m0, float4& m1, float4& m2, float4& m3)
{
    float pv, f;
    pv = 1.0f / m0.x;
    m0.y *= pv; m0.z *= pv; m0.w *= pv; m0.x = pv;
    f = m1.x; m1.y = fmaf(-f, m0.y, m1.y); m1.z = fmaf(-f, m0.z, m1.z); m1.w = fmaf(-f, m0.w, m1.w); m1.x = -f * pv;
    f = m2.x; m2.y = fmaf(-f, m0.y, m2.y); m2.z = fmaf(-f, m0.z, m2.z); m2.w = fmaf(-f, m0.w, m2.w); m2.x = -f * pv;
    f = m3.x; m3.y = fmaf(-f, m0.y, m3.y); m3.z = fmaf(-f, m0.z, m3.z); m3.w = fmaf(-f, m0.w, m3.w); m3.x = -f * pv;
    pv = 1.0f / m1.y;
    m1.x *= pv; m1.z *= pv; m1.w *= pv; m1.y = pv;
    f = m0.y; m0.x = fmaf(-f, m1.x, m0.x); m0.z = fmaf(-f, m1.z, m0.z); m0.w = fmaf(-f, m1.w, m0.w); m0.y = -f * pv;
    f = m2.y; m2.x = fmaf(-f, m1.x, m2.x); m2.z = fmaf(-f, m1.z, m2.z); m2.w = fmaf(-f, m1.w, m2.w); m2.y = -f * pv;
    f = m3.y; m3.x = fmaf(-f, m1.x, m3.x); m3.z = fmaf(-f, m1.z, m3.z); m3.w = fmaf(-f, m1.w, m3.w); m3.y = -f * pv;
    pv = 1.0f / m2.z;
    m2.x *= pv; m2.y *= pv; m2.w *= pv; m2.z = pv;
    f = m0.z; m0.x = fmaf(-f, m2.x, m0.x); m0.y = fmaf(-f, m2.y, m0.y); m0.w = fmaf(-f, m2.w, m0.w); m0.z = -f * pv;
    f = m1.z; m1.x = fmaf(-f, m2.x, m1.x); m1.y = fmaf(-f, m2.y, m1.y); m1.w = fmaf(-f, m2.w, m1.w); m1.z = -f * pv;
    f = m3.z; m3.x = fmaf(-f, m2.x, m3.x); m3.y = fmaf(-f, m2.y, m3.y); m3.w = fmaf(-f, m2.w, m3.w); m3.z = -f * pv;
    pv = 1.0f / m3.w;
    m3.x *= pv; m3.y *= pv; m3.z *= pv; m3.w = pv;
    f = m0.w; m0.x = fmaf(-f, m3.x, m0.x); m0.y = fmaf(-f, m3.y, m0.y); m0.z = fmaf(-f, m3.z, m0.z); m0.w = -f * pv;
    f = m1.w; m1.x = fmaf(-f, m3.x, m1.x); m1.y = fmaf(-f, m3.y, m1.y); m1.z = fmaf(-f, m3.z, m1.z); m1.w = -f * pv;
    f = m2.w; m2.x = fmaf(-f, m3.x, m2.x); m2.y = fmaf(-f, m3.y, m2.y); m2.z = fmaf(-f, m3.z, m2.z); m2.w = -f * pv;
}

// ---- named-register slab: 15 float4 members, all access compile-time -------
struct Slab {
    float4 v0, v1, v2, v3, v4, v5, v6, v7, v8, v9, v10, v11, v12, v13, v14;
};
template<int I> __device__ __forceinline__ float4& AT(Slab& s) {
    if constexpr (I == 0) return s.v0;   else if constexpr (I == 1) return s.v1;
    else if constexpr (I == 2) return s.v2;  else if constexpr (I == 3) return s.v3;
    else if constexpr (I == 4) return s.v4;  else if constexpr (I == 5) return s.v5;
    else if constexpr (I == 6) return s.v6;  else if constexpr (I == 7) return s.v7;
    else if constexpr (I == 8) return s.v8;  else if constexpr (I == 9) return s.v9;
    else if constexpr (I == 10) return s.v10; else if constexpr (I == 11) return s.v11;
    else if constexpr (I == 12) return s.v12; else if constexpr (I == 13) return s.v13;
    else return s.v14;
}
template<int Q = 0> __device__ __forceinline__ void slab_load(Slab& s, const float* src) {
    if constexpr (Q < 15) { AT<Q>(s) = *(const float4*)(src + 4 * Q); slab_load<Q + 1>(s, src); }
}
template<int Q = 0> __device__ __forceinline__ void slab_store(Slab& s, float* dst) {
    if constexpr (Q < 15) { *(float4*)(dst + 4 * Q) = AT<Q>(s); slab_store<Q + 1>(s, dst); }
}
template<int Q = 0> __device__ __forceinline__ void slab_stage(Slab& s, float4 (&dst)[15]) {
    if constexpr (Q < 15) { dst[Q] = AT<Q>(s); slab_stage<Q + 1>(s, dst); }
}
template<int KB, int Q = 0> __device__ __forceinline__ void zero_except(Slab& s) {
    if constexpr (Q < 15) {
        if constexpr (Q != KB) AT<Q>(s) = make_float4(0.f, 0.f, 0.f, 0.f);
        zero_except<KB, Q + 1>(s);
    }
}
template<int KB, int Q = 0>
__device__ __forceinline__ void rank4(Slab& s, const float4 sc, const float4 (&pb)[4][15]) {
    if constexpr (Q < 15) {
        if constexpr (Q != KB) {
            const float4 p0 = pb[0][Q], p1 = pb[1][Q], p2 = pb[2][Q], p3 = pb[3][Q];
            float4& r = AT<Q>(s);
            r.x = fmaf(sc.x, p0.x, fmaf(sc.y, p1.x, fmaf(sc.z, p2.x, fmaf(sc.w, p3.x, r.x))));
            r.y = fmaf(sc.x, p0.y, fmaf(sc.y, p1.y, fmaf(sc.z, p2.y, fmaf(sc.w, p3.y, r.y))));
            r.z = fmaf(sc.x, p0.z, fmaf(sc.y, p1.z, fmaf(sc.z, p2.z, fmaf(sc.w, p3.z, r.z))));
            r.w = fmaf(sc.x, p0.w, fmaf(sc.y, p1.w, fmaf(sc.z, p2.w, fmaf(sc.w, p3.w, r.w))));
        }
        rank4<KB, Q + 1>(s, sc, pb);
    }
}
template<int Q = 0>
__device__ __forceinline__ void slab_store_fin(Slab& s, float* dst, int r, int j0,
                                               float c, float c2) {
    if constexpr (Q < 15) {
        const int cg = j0 + 4 * Q;
        const float4 v = AT<Q>(s);
        float4 o;
        o.x = ((r == cg + 0) ? c : 0.f) - c2 * v.x;
        o.y = ((r == cg + 1) ? c : 0.f) - c2 * v.y;
        o.z = ((r == cg + 2) ? c : 0.f) - c2 * v.z;
        o.w = ((r == cg + 3) ? c : 0.f) - c2 * v.w;
        *(float4*)(dst + 4 * Q) = o;
        slab_store_fin<Q + 1>(s, dst, r, j0, c, c2);
    }
}

template<int KB>
__device__ __forceinline__ void gj_step(Slab& s, int r, int rel, float4 (&praw)[2][4][15])
{
    const int buf = KB & 1;
    float4 m0 = praw[buf][0][KB];
    float4 m1 = praw[buf][1][KB];
    float4 m2 = praw[buf][2][KB];
    float4 m3 = praw[buf][3][KB];
    inv4(m0, m1, m2, m3);
    if (r < D) {
        const bool is_piv = (rel >= 4 * KB) && (rel < 4 * KB + 4);
        float4 sc;
        if (is_piv) {
            const int i = rel - 4 * KB;
            sc = (i == 0) ? m0 : (i == 1) ? m1 : (i == 2) ? m2 : m3;
            zero_except<KB>(s);
        } else {
            const float4 fr = AT<KB>(s);
            sc.x = -(fr.x * m0.x + fr.y * m1.x + fr.z * m2.x + fr.w * m3.x);
            sc.y = -(fr.x * m0.y + fr.y * m1.y + fr.z * m2.y + fr.w * m3.y);
            sc.z = -(fr.x * m0.z + fr.y * m1.z + fr.z * m2.z + fr.w * m3.z);
            sc.w = -(fr.x * m0.w + fr.y * m1.w + fr.z * m2.w + fr.w * m3.w);
        }
        rank4<KB>(s, sc, praw[buf]);
        AT<KB>(s) = sc;
        if (KB < 14 && rel >= 4 * (KB + 1) && rel < 4 * (KB + 1) + 4) {
            slab_stage(s, praw[buf ^ 1][rel - 4 * (KB + 1)]);
        }
    }
    __syncthreads();
}

template<int KB> struct GJ {
    __device__ static __forceinline__ void run(Slab& s, int r, int rel,
                                               float4 (&praw)[2][4][15]) {
        gj_step<KB>(s, r, rel, praw);
        GJ<KB + 1>::run(s, r, rel, praw);
    }
};
template<> struct GJ<15> {
    __device__ static __forceinline__ void run(Slab&, int, int, float4 (&)[2][4][15]) {}
};

__device__ __forceinline__ void do_factor(float* M, float* rb, int ag, int p,
                                          float c, float c2, float4 (&praw)[2][4][15])
{
    const int j0 = p * NB;
    const int r = threadIdx.x;
    const int rel = r - j0;
    Slab s;
    if (r < D) slab_load(s, M + (size_t)r * D + j0);
    if (rel >= 0 && rel < 4) slab_stage(s, praw[0][rel]);
    __syncthreads();
    GJ<0>::run(s, r, rel, praw);
    if (r < D) {
        float* dst = M + (size_t)r * D + j0;
        if (p == NPAN - 1) {
            slab_store_fin(s, dst, r, j0, c, c2);
        } else {
            slab_store(s, dst);
            const int nrel = r - NB * (p + 1);
            if (nrel >= 0 && nrel < NB)
                slab_store(s, rb + RBOFF((p + 1) & 1, ag, p) + nrel * NB);
        }
    }
}

// -------- update tiles: M[rt,ct] = (rt==p?0:M) + F*R -------------------------
__device__ __forceinline__ void mm_row(const float4 a, const float4 b0, const float4 b1,
                                       const float4 b2, const float4 b3, float acc[4]) {
    acc[0] = fmaf(a.x, b0.x, fmaf(a.y, b1.x, fmaf(a.z, b2.x, fmaf(a.w, b3.x, acc[0]))));
    acc[1] = fmaf(a.x, b0.y, fmaf(a.y, b1.y, fmaf(a.z, b2.y, fmaf(a.w, b3.y, acc[1]))));
    acc[2] = fmaf(a.x, b0.z, fmaf(a.y, b1.z, fmaf(a.z, b2.z, fmaf(a.w, b3.z, acc[2]))));
    acc[3] = fmaf(a.x, b0.w, fmaf(a.y, b1.w, fmaf(a.z, b2.w, fmaf(a.w, b3.w, acc[3]))));
}

__device__ __forceinline__ void do_update(float* M, float* rb, int ag, int s, int p,
                                          float c, float c2,
                                          float (&R)[NB][NB + 8], float (&F)[NB][NB + 8])
{
    const int t = threadIdx.x;
    const int tx = t % 16, ty = t / 16;
    const int j0 = p * NB;
    for (int tile = s; tile < 30; tile += 4) {
        const int cti = tile / 6;
        const int ct = cti + (cti >= p ? 1 : 0);
        const int rt = tile % 6;
        const int c0 = ct * NB, r0 = rt * NB;
        __syncthreads();   // protect LDS from previous tile's readers
        {   // stage R from the race-free stash
            const float* rsrc = rb + RBOFF(p & 1, ag, ct);
            for (int idx = t; idx < NB * 15; idx += 384) {
                int k = idx / 15, qq = idx % 15;
                *(float4*)&R[k][4 * qq] = *(const float4*)(rsrc + k * NB + 4 * qq);
            }
        }
        {   // stage F (factored panel rows r0..r0+59)
            for (int idx = t; idx < NB * 15; idx += 384) {
                int rr = idx / 15, qq = idx % 15;
                float4 v = *(const float4*)(M + (size_t)(r0 + rr) * D + j0 + 4 * qq);
                if (p == NPAN - 1) {   // recover raw F from transformed panel
                    const int rg = r0 + rr, cg = j0 + 4 * qq;
                    v.x = (((rg == cg + 0) ? c : 0.f) - v.x) / c2;
                    v.y = (((rg == cg + 1) ? c : 0.f) - v.y) / c2;
                    v.z = (((rg == cg + 2) ? c : 0.f) - v.z) / c2;
                    v.w = (((rg == cg + 3) ? c : 0.f) - v.w) / c2;
                }
                *(float4*)&F[rr][4 * qq] = v;
            }
        }
        __syncthreads();
        if (tx < 15 && ty < 15) {
            float acc[4][4];
            #pragma unroll
            for (int i = 0; i < 4; ++i)
                #pragma unroll
                for (int j = 0; j < 4; ++j) acc[i][j] = 0.0f;
            for (int kq = 0; kq < 15; ++kq) {
                float4 a0 = *(const float4*)&F[4 * ty + 0][4 * kq];
                float4 a1 = *(const float4*)&F[4 * ty + 1][4 * kq];
                float4 a2 = *(const float4*)&F[4 * ty + 2][4 * kq];
                float4 a3 = *(const float4*)&F[4 * ty + 3][4 * kq];
                float4 b0 = *(const float4*)&R[4 * kq + 0][4 * tx];
                float4 b1 = *(const float4*)&R[4 * kq + 1][4 * tx];
                float4 b2 = *(const float4*)&R[4 * kq + 2][4 * tx];
                float4 b3 = *(const float4*)&R[4 * kq + 3][4 * tx];
                mm_row(a0, b0, b1, b2, b3, acc[0]);
                mm_row(a1, b0, b1, b2, b3, acc[1]);
                mm_row(a2, b0, b1, b2, b3, acc[2]);
                mm_row(a3, b0, b1, b2, b3, acc[3]);
            }
            #pragma unroll
            for (int i = 0; i < 4; ++i) {
                const int rg = r0 + 4 * ty + i;
                float* dst = M + (size_t)rg * D + c0 + 4 * tx;
                float4 base;
                if (rt == p) { base = make_float4(0.f, 0.f, 0.f, 0.f); }
                else         { base = *(const float4*)dst; }
                float4 v;
                v.x = base.x + acc[i][0];
                v.y = base.y + acc[i][1];
                v.z = base.z + acc[i][2];
                v.w = base.w + acc[i][3];
                if (p < NPAN - 1) {
                    if (rt == p + 1 && ct != p + 1) {  // stash next pass's R slice
                        float* rdst = rb + RBOFF((p + 1) & 1, ag, ct) + (4 * ty + i) * NB + 4 * tx;
                        *(float4*)rdst = v;
                    }
                    *(float4*)dst = v;
                } else {                               // fold finalize on last pass
                    const int cg = c0 + 4 * tx;
                    float4 o;
                    o.x = ((rg == cg + 0) ? c : 0.f) - c2 * v.x;
                    o.y = ((rg == cg + 1) ? c : 0.f) - c2 * v.y;
                    o.z = ((rg == cg + 2) ? c : 0.f) - c2 * v.z;
                    o.w = ((rg == cg + 3) ? c : 0.f) - c2 * v.w;
                    *(float4*)dst = o;
                }
            }
        }
    }
}

// ------- mean: m = obs - c*Sinv*d, via transformed C:  m = obs - d + (C^T d)/c
__device__ __forceinline__ void do_mean(float* out, const float* mean_in,
                                        const float* obs, int ag, float c,
                                        float (&dsh)[D])
{
    const float* C = out + COV_OFF + (size_t)ag * D * D;
    const int t = threadIdx.x;
    if (t < D) dsh[t] = obs[ag * D + t] - mean_in[ag * D + gshift(t)];
    __syncthreads();
    if (t < D) {
        float dot = 0.0f;
        #pragma unroll 8
        for (int j = 0; j < D; ++j)
            dot = fmaf(C[(size_t)j * D + t], dsh[j], dot);
        out[ag * D + t] = obs[ag * D + t] - dsh[t] + dot / c;
    }
}

// ---------------- the single fused kernel -----------------------------------
__global__ __launch_bounds__(384) void fused_kernel(
    const float* __restrict__ P, const float* __restrict__ mean_in,
    const float* __restrict__ obs, const float* __restrict__ rs,
    const int* __restrict__ init_f, const int* __restrict__ sel_f,
    float* __restrict__ out, float* __restrict__ rb, unsigned* __restrict__ sync)
{
    const int wid = blockIdx.x;
    const int ag = wid >> 2;
    const int s  = wid & 3;
    const int t  = threadIdx.x;
    const bool ini = init_f[ag] != 0, sel = sel_f[ag] != 0;
    const bool act = ini && sel;
    const float c = rs[ag] + 1.0f;
    const float c2 = c * c;
    const float* Pa = P + (size_t)ag * D * D;
    float* cov = out + COV_OFF + (size_t)ag * D * D;
    unsigned* cnt = sync;
    unsigned* gen = sync + 1;

    __shared__ float4 praw[2][4][15];
    __shared__ float  Rsh[NB][NB + 8];
    __shared__ float  Fsh[NB][NB + 8];
    __shared__ float  dsh[D];

    // ---- BUILD: rows [s*90, s*90+90) ----
    if (t < D) {
        const int j = t;
        if (act) {
            const int gj = gshift(j);
            #pragma unroll 2
            for (int k = 0; k < 90; ++k) {
                const int i = s * 90 + k;
                float v = Pa[(size_t)gshift(i) * D + gj];
                if (i == j) v += 1.0f + c;
                cov[(size_t)i * D + j] = v;
                if (i < NB && j >= NB)
                    rb[RBOFF(0, ag, j / NB) + i * NB + (j % NB)] = v;
            }
        } else if (sel) {
            #pragma unroll 2
            for (int k = 0; k < 90; ++k) {
                const int i = s * 90 + k;
                cov[(size_t)i * D + j] = Pa[(size_t)i * D + j] + ((i == j) ? c : 0.0f);
            }
        } else {
            #pragma unroll 2
            for (int k = 0; k < 90; ++k) {
                const int i = s * 90 + k;
                cov[(size_t)i * D + j] = Pa[(size_t)i * D + j];
            }
        }
    }
    if (s == 3) {
        if (t < D) out[ag * D + t] = (sel && !ini) ? obs[ag * D + t] : mean_in[ag * D + t];
        if (t == D) out[INIT_OFF + ag] = (ini || sel) ? 1.0f : 0.0f;
    }
    gridsync(cnt, gen);

    // ---- 6 factor/update passes ----
    for (int p = 0; p < NPAN; ++p) {
        if (s == 0 && act) do_factor(cov, rb, ag, p, c, c2, praw);
        gridsync(cnt, gen);
        if (act) do_update(cov, rb, ag, s, p, c, c2, Rsh, Fsh);
        gridsync(cnt, gen);
    }

    // ---- mean ----
    if (s == 0 && act) do_mean(out, mean_in, obs, ag, c, dsh);
}

extern "C" void kernel_launch(void* const* d_in, const int* in_sizes, int n_in,
                              void* d_out, int out_size, void* d_ws, size_t ws_size,
                              hipStream_t stream) {
    const float* mean_in     = (const float*)d_in[0];
    const float* P           = (const float*)d_in[1];
    const float* obs         = (const float*)d_in[2];
    const float* rs          = (const float*)d_in[3];
    const int*   initialized = (const int*)d_in[4];
    const int*   selected    = (const int*)d_in[5];
    float* out = (float*)d_out;
    float* rb  = (float*)d_ws;                           // 11.06 MB R stash
    unsigned* syncp = (unsigned*)((float*)d_ws + SYNC_OFF);

    hipMemsetAsync(syncp, 0, 2 * sizeof(unsigned), stream);
    fused_kernel<<<NWG, 384, 0, stream>>>(P, mean_in, obs, rs, initialized, selected,
                                          out, rb, syncp);
}

// Round 9
// 381.303 us; speedup vs baseline: 4.4970x; 4.4970x over previous
//
#include <hip/hip_runtime.h>

#define D 360
#define NAG 64
#define NB 120
#define NPAN 3
#define NQG 30                       // float4 per 120-col panel row
#define COV_OFF (NAG * D)
#define INIT_OFF (COV_OFF + NAG * D * D)
// R stash in d_ws: [parity][agent][slot 0..3][120 rows][60 cols]
#define SB(par, ag, slot) ((((size_t)(par) * NAG + (ag)) * 4 + (slot)) * 7200)

__device__ __forceinline__ int gshift(int i) {
    return ((i % 60) < 58) ? (i + 2) : i;
}

// ------- build: S (upd) / final cov (others) + mean/flag + R0 stash ---------
__global__ __launch_bounds__(384) void build_kernel(
    const float* __restrict__ P, const float* __restrict__ mean_in,
    const float* __restrict__ obs, const float* __restrict__ rs,
    const int* __restrict__ init_f, const int* __restrict__ sel_f,
    float* __restrict__ out, float* __restrict__ rb)
{
    const int by = blockIdx.x, ag = blockIdx.y, t = threadIdx.x;
    const bool ini = init_f[ag] != 0, sel = sel_f[ag] != 0;
    const float c = rs[ag] + 1.0f;
    if (by == 45) {   // fused "small" block: mean passthrough/init + flag
        if (t < D) {
            float v = (sel && !ini) ? obs[ag * D + t] : mean_in[ag * D + t];
            out[ag * D + t] = v;     // upd agents overwritten by solve_mean
        }
        if (t == 0) out[INIT_OFF + ag] = (ini || sel) ? 1.0f : 0.0f;
        return;
    }
    if (t >= D) return;
    const float* Pa = P + (size_t)ag * D * D;
    float* cov = out + COV_OFF + (size_t)ag * D * D;
    const int j = t;
    if (sel && ini) {
        const int gj = gshift(j);
        #pragma unroll
        for (int s = 0; s < 8; ++s) {
            const int i = by * 8 + s;
            float v = Pa[(size_t)gshift(i) * D + gj];
            if (i == j) v += 1.0f + c;           // + process(1) + obs(c)
            cov[(size_t)i * D + j] = v;
            if (i < NB && j >= NB)               // stash R slices for pass 0
                rb[SB(0, ag, j / 60 - 2) + i * 60 + (j % 60)] = v;
        }
    } else if (sel) {
        #pragma unroll
        for (int s = 0; s < 8; ++s) {
            const int i = by * 8 + s;
            cov[(size_t)i * D + j] = Pa[(size_t)i * D + j] + ((i == j) ? c : 0.0f);
        }
    } else {
        #pragma unroll
        for (int s = 0; s < 8; ++s) {
            const int i = by * 8 + s;
            cov[(size_t)i * D + j] = Pa[(size_t)i * D + j];
        }
    }
}

// ---------------- 4x4 in-place GJ inverse (no pivoting; SPD blocks) ----------
__device__ __forceinline__ void inv4(float4& m0, float4& m1, float4& m2, float4& m3)
{
    float pv, f;
    pv = 1.0f / m0.x;
    m0.y *= pv; m0.z *= pv; m0.w *= pv; m0.x = pv;
    f = m1.x; m1.y = fmaf(-f, m0.y, m1.y); m1.z = fmaf(-f, m0.z, m1.z); m1.w = fmaf(-f, m0.w, m1.w); m1.x = -f * pv;
    f = m2.x; m2.y = fmaf(-f, m0.y, m2.y); m2.z = fmaf(-f, m0.z, m2.z); m2.w = fmaf(-f, m0.w, m2.w); m2.x = -f * pv;
    f = m3.x; m3.y = fmaf(-f, m0.y, m3.y); m3.z = fmaf(-f, m0.z, m3.z); m3.w = fmaf(-f, m0.w, m3.w); m3.x = -f * pv;
    pv = 1.0f / m1.y;
    m1.x *= pv; m1.z *= pv; m1.w *= pv; m1.y = pv;
    f = m0.y; m0.x = fmaf(-f, m1.x, m0.x); m0.z = fmaf(-f, m1.z, m0.z); m0.w = fmaf(-f, m1.w, m0.w); m0.y = -f * pv;
    f = m2.y; m2.x = fmaf(-f, m1.x, m2.x); m2.z = fmaf(-f, m1.z, m2.z); m2.w = fmaf(-f, m1.w, m2.w); m2.y = -f * pv;
    f = m3.y; m3.x = fmaf(-f, m1.x, m3.x); m3.z = fmaf(-f, m1.z, m3.z); m3.w = fmaf(-f, m1.w, m3.w); m3.y = -f * pv;
    pv = 1.0f / m2.z;
    m2.x *= pv; m2.y *= pv; m2.w *= pv; m2.z = pv;
    f = m0.z; m0.x = fmaf(-f, m2.x, m0.x); m0.y = fmaf(-f, m2.y, m0.y); m0.w = fmaf(-f, m2.w, m0.w); m0.z = -f * pv;
    f = m1.z; m1.x = fmaf(-f, m2.x, m1.x); m1.y = fmaf(-f, m2.y, m1.y); m1.w = fmaf(-f, m2.w, m1.w); m1.z = -f * pv;
    f = m3.z; m3.x = fmaf(-f, m2.x, m3.x); m3.y = fmaf(-f, m2.y, m3.y); m3.w = fmaf(-f, m2.w, m3.w); m3.z = -f * pv;
    pv = 1.0f / m3.w;
    m3.x *= pv; m3.y *= pv; m3.z *= pv; m3.w = pv;
    f = m0.w; m0.x = fmaf(-f, m3.x, m0.x); m0.y = fmaf(-f, m3.y, m0.y); m0.z = fmaf(-f, m3.z, m0.z); m0.w = -f * pv;
    f = m1.w; m1.x = fmaf(-f, m3.x, m1.x); m1.y = fmaf(-f, m3.y, m1.y); m1.z = fmaf(-f, m3.z, m1.z); m1.w = -f * pv;
    f = m2.w; m2.x = fmaf(-f, m3.x, m2.x); m2.y = fmaf(-f, m3.y, m2.y); m2.z = fmaf(-f, m3.z, m2.z); m2.w = -f * pv;
}

// ---- named-register slab: 15 float4 members, all access compile-time -------
struct Slab {
    float4 v0, v1, v2, v3, v4, v5, v6, v7, v8, v9, v10, v11, v12, v13, v14;
};
template<int I> __device__ __forceinline__ float4& AT(Slab& s) {
    if constexpr (I == 0) return s.v0;   else if constexpr (I == 1) return s.v1;
    else if constexpr (I == 2) return s.v2;  else if constexpr (I == 3) return s.v3;
    else if constexpr (I == 4) return s.v4;  else if constexpr (I == 5) return s.v5;
    else if constexpr (I == 6) return s.v6;  else if constexpr (I == 7) return s.v7;
    else if constexpr (I == 8) return s.v8;  else if constexpr (I == 9) return s.v9;
    else if constexpr (I == 10) return s.v10; else if constexpr (I == 11) return s.v11;
    else if constexpr (I == 12) return s.v12; else if constexpr (I == 13) return s.v13;
    else return s.v14;
}
template<int Q = 0> __device__ __forceinline__ void slab_load(Slab& s, const float* src) {
    if constexpr (Q < 15) { AT<Q>(s) = *(const float4*)(src + 4 * Q); slab_load<Q + 1>(s, src); }
}
template<int Q = 0> __device__ __forceinline__ void slab_store(Slab& s, float* dst) {
    if constexpr (Q < 15) { *(float4*)(dst + 4 * Q) = AT<Q>(s); slab_store<Q + 1>(s, dst); }
}
template<int Q = 0> __device__ __forceinline__ void stage_row(Slab& s, float4* rowp) {
    if constexpr (Q < 15) { rowp[Q] = AT<Q>(s); stage_row<Q + 1>(s, rowp); }
}
template<int Q = 0> __device__ __forceinline__ void zero_all(Slab& s) {
    if constexpr (Q < 15) { AT<Q>(s) = make_float4(0.f, 0.f, 0.f, 0.f); zero_all<Q + 1>(s); }
}
// rank-4 update over the thread's 15 local cols; praw indexed at OFF+q; skip SKIP
template<int OFF, int SKIP, int Q = 0>
__device__ __forceinline__ void rank4g(Slab& s, const float4 sc, const float4 (&pb)[4][NQG]) {
    if constexpr (Q < 15) {
        if constexpr (Q != SKIP) {
            const float4 p0 = pb[0][OFF + Q], p1 = pb[1][OFF + Q],
                         p2 = pb[2][OFF + Q], p3 = pb[3][OFF + Q];
            float4& r = AT<Q>(s);
            r.x = fmaf(sc.x, p0.x, fmaf(sc.y, p1.x, fmaf(sc.z, p2.x, fmaf(sc.w, p3.x, r.x))));
            r.y = fmaf(sc.x, p0.y, fmaf(sc.y, p1.y, fmaf(sc.z, p2.y, fmaf(sc.w, p3.y, r.y))));
            r.z = fmaf(sc.x, p0.z, fmaf(sc.y, p1.z, fmaf(sc.z, p2.z, fmaf(sc.w, p3.z, r.z))));
            r.w = fmaf(sc.x, p0.w, fmaf(sc.y, p1.w, fmaf(sc.z, p2.w, fmaf(sc.w, p3.w, r.w))));
        }
        rank4g<OFF, SKIP, Q + 1>(s, sc, pb);
    }
}
// transformed final store for the last panel: o = (r==cg ? c:0) - c2*v
template<int Q = 0>
__device__ __forceinline__ void slab_store_fin(Slab& s, float* dst, int r, int j0h,
                                               float c, float c2) {
    if constexpr (Q < 15) {
        const int cg = j0h + 4 * Q;
        const float4 v = AT<Q>(s);
        float4 o;
        o.x = ((r == cg + 0) ? c : 0.f) - c2 * v.x;
        o.y = ((r == cg + 1) ? c : 0.f) - c2 * v.y;
        o.z = ((r == cg + 2) ? c : 0.f) - c2 * v.z;
        o.w = ((r == cg + 3) ? c : 0.f) - c2 * v.w;
        *(float4*)(dst + 4 * Q) = o;
        slab_store_fin<Q + 1>(s, dst, r, j0h, c, c2);
    }
}

// ------ factor: 768-thread (row, half) block-pivot GJ on 360x120 panel ------
// thread (r, h): h = t>=384 (wave-uniform). Slab15 = cols [h*60, h*60+60).
// praw: raw pivot rows (full 120 cols), staged one step ahead (dbuf).
// fcol: pivot-col float4 per row for the CURRENT step, staged one step ahead.
template<int KB>
__device__ __forceinline__ void gj_step(Slab& s, int r, int rel, int h,
                                        float4 (&praw)[2][4][NQG],
                                        float4 (&fcol)[2][D])
{
    constexpr int BUF = KB & 1;
    constexpr int H = KB / 15;
    constexpr int Q = KB % 15;
    float4 m0 = praw[BUF][0][KB], m1 = praw[BUF][1][KB],
           m2 = praw[BUF][2][KB], m3 = praw[BUF][3][KB];
    inv4(m0, m1, m2, m3);
    if (r < D) {
        const bool ispiv = (rel >= 4 * KB) && (rel < 4 * KB + 4);
        float4 sc;
        if (ispiv) {
            const int i = rel - 4 * KB;
            sc = (i == 0) ? m0 : (i == 1) ? m1 : (i == 2) ? m2 : m3;  // Binv row
            zero_all(s);
        } else {
            const float4 fr = fcol[BUF][r];       // raw pivot-col coeffs of row r
            sc.x = -(fr.x * m0.x + fr.y * m1.x + fr.z * m2.x + fr.w * m3.x);
            sc.y = -(fr.x * m0.y + fr.y * m1.y + fr.z * m2.y + fr.w * m3.y);
            sc.z = -(fr.x * m0.z + fr.y * m1.z + fr.z * m2.z + fr.w * m3.z);
            sc.w = -(fr.x * m0.w + fr.y * m1.w + fr.z * m2.w + fr.w * m3.w);
        }
        if (h == H) {                  // wave-uniform branch
            rank4g<H * 15, Q>(s, sc, praw[BUF]);
            AT<Q>(s) = sc;
        } else {
            rank4g<(1 - H) * 15, -1>(s, sc, praw[BUF]);
        }
        if constexpr (KB < NQG - 1) {
            constexpr int H2 = (KB + 1) / 15;
            constexpr int Q2 = (KB + 1) % 15;
            if (h == H2) fcol[BUF ^ 1][r] = AT<Q2>(s);
            const int nrel = rel - 4 * (KB + 1);
            if (nrel >= 0 && nrel < 4) stage_row(s, &praw[BUF ^ 1][nrel][h * 15]);
        }
    }
    __syncthreads();
}

template<int KB> struct GJ {
    static __device__ __forceinline__ void run(Slab& s, int r, int rel, int h,
                                               float4 (&praw)[2][4][NQG],
                                               float4 (&fcol)[2][D]) {
        gj_step<KB>(s, r, rel, h, praw, fcol);
        GJ<KB + 1>::run(s, r, rel, h, praw, fcol);
    }
};
template<> struct GJ<NQG> {
    static __device__ __forceinline__ void run(Slab&, int, int, int,
                                               float4 (&)[2][4][NQG], float4 (&)[2][D]) {}
};

__global__ __launch_bounds__(768, 3) void factor_kernel(
    float* __restrict__ out, const float* __restrict__ rs,
    const int* __restrict__ init_f, const int* __restrict__ sel_f,
    float* __restrict__ rb, int p)
{
    const int ag = blockIdx.x;
    if (!(init_f[ag] && sel_f[ag])) return;
    float* M = out + COV_OFF + (size_t)ag * D * D;
    const int j0 = p * NB;
    const int t = threadIdx.x;
    const int h = (t >= 384) ? 1 : 0;     // wave-uniform half
    const int r = t - 384 * h;            // row, active r<360
    const int rel = r - j0;
    __shared__ float4 praw[2][4][NQG];    // 3.84 KB
    __shared__ float4 fcol[2][D];         // 11.5 KB
    Slab s;
    if (r < D) {
        slab_load(s, M + (size_t)r * D + j0 + h * 60);
        if (rel >= 0 && rel < 4) stage_row(s, &praw[0][rel][h * 15]);
        if (h == 0) fcol[0][r] = s.v0;    // KB=0: H=0, Q=0
    }
    __syncthreads();
    GJ<0>::run(s, r, rel, h, praw, fcol);
    const float c = rs[ag] + 1.0f;
    const float c2 = c * c;
    if (r < D) {
        const int j0h = j0 + h * 60;
        float* dst = M + (size_t)r * D + j0h;
        if (p == NPAN - 1) {
            // last panel: fold finalize  cov = c*I - c^2 * Sinv  on panel cols
            slab_store_fin(s, dst, r, j0h, c, c2);
        } else {
            slab_store(s, dst);
            // stash next pass's R slices (rows of next panel, this col half)
            const int nrel = r - NB * (p + 1);
            if (nrel >= 0 && nrel < NB)
                slab_store(s, rb + SB((p + 1) & 1, ag, 2 * p + h) + nrel * 60);
        }
    }
}

// -------- update: M[rt,ct] = (panelrow?0:M) + F*R ; K=120 -------------------
__device__ __forceinline__ void mm_row(const float4 a, const float4 b0, const float4 b1,
                                       const float4 b2, const float4 b3, float acc[4]) {
    acc[0] = fmaf(a.x, b0.x, fmaf(a.y, b1.x, fmaf(a.z, b2.x, fmaf(a.w, b3.x, acc[0]))));
    acc[1] = fmaf(a.x, b0.y, fmaf(a.y, b1.y, fmaf(a.z, b2.y, fmaf(a.w, b3.y, acc[1]))));
    acc[2] = fmaf(a.x, b0.z, fmaf(a.y, b1.z, fmaf(a.z, b2.z, fmaf(a.w, b3.z, acc[2]))));
    acc[3] = fmaf(a.x, b0.w, fmaf(a.y, b1.w, fmaf(a.z, b2.w, fmaf(a.w, b3.w, acc[3]))));
}

__global__ __launch_bounds__(256) void update_kernel(
    float* __restrict__ out, const float* __restrict__ rs,
    const int* __restrict__ init_f, const int* __restrict__ sel_f,
    float* __restrict__ rb, int p)
{
    const int ag = blockIdx.x;
    if (!(init_f[ag] && sel_f[ag])) return;
    const int y = blockIdx.y;                    // 0..3
    const int ct = y + (y >= 2 * p ? 2 : 0);     // global 60-col tile, skip panel
    const int rt = blockIdx.z;                   // 0..5 (60-row tile)
    const int r0 = 60 * rt, c0 = 60 * ct;
    const bool panelrow = ((rt >> 1) == p);
    float* M = out + COV_OFF + (size_t)ag * D * D;
    const float c = rs[ag] + 1.0f;
    const float c2 = c * c;
    __shared__ float R[NB][60];      // [k][j]  K=120
    __shared__ float F[60][NB + 4];  // [r][k]
    const int t = threadIdx.x;
    {   // R from the race-free stash
        const float* rsrc = rb + SB(p & 1, ag, y);
        for (int idx = t; idx < 120 * 15; idx += 256) {
            const int k = idx / 15, q = idx % 15;
            *(float4*)&R[k][4 * q] = *(const float4*)(rsrc + k * 60 + 4 * q);
        }
    }
    {   // F = factored panel, rows r0..r0+59
        for (int idx = t; idx < 60 * NQG; idx += 256) {
            const int row = idx / NQG, q = idx % NQG;
            float4 v = *(const float4*)(M + (size_t)(r0 + row) * D + p * NB + 4 * q);
            if (p == NPAN - 1) {
                // factor already wrote transformed panel: recover raw F
                const int rg = r0 + row, cg = p * NB + 4 * q;
                v.x = (((rg == cg + 0) ? c : 0.f) - v.x) / c2;
                v.y = (((rg == cg + 1) ? c : 0.f) - v.y) / c2;
                v.z = (((rg == cg + 2) ? c : 0.f) - v.z) / c2;
                v.w = (((rg == cg + 3) ? c : 0.f) - v.w) / c2;
            }
            *(float4*)&F[row][4 * q] = v;
        }
    }
    __syncthreads();
    const int tx = t % 16, ty = t / 16;
    if (tx < 15 && ty < 15) {
        float acc[4][4];
        #pragma unroll
        for (int i = 0; i < 4; ++i)
            #pragma unroll
            for (int j = 0; j < 4; ++j) acc[i][j] = 0.0f;
        for (int kq = 0; kq < NQG; ++kq) {
            float4 a0 = *(const float4*)&F[4 * ty + 0][4 * kq];
            float4 a1 = *(const float4*)&F[4 * ty + 1][4 * kq];
            float4 a2 = *(const float4*)&F[4 * ty + 2][4 * kq];
            float4 a3 = *(const float4*)&F[4 * ty + 3][4 * kq];
            float4 b0 = *(const float4*)&R[4 * kq + 0][4 * tx];
            float4 b1 = *(const float4*)&R[4 * kq + 1][4 * tx];
            float4 b2 = *(const float4*)&R[4 * kq + 2][4 * tx];
            float4 b3 = *(const float4*)&R[4 * kq + 3][4 * tx];
            mm_row(a0, b0, b1, b2, b3, acc[0]);
            mm_row(a1, b0, b1, b2, b3, acc[1]);
            mm_row(a2, b0, b1, b2, b3, acc[2]);
            mm_row(a3, b0, b1, b2, b3, acc[3]);
        }
        #pragma unroll
        for (int i = 0; i < 4; ++i) {
            const int rg = r0 + 4 * ty + i;
            float* dst = M + (size_t)rg * D + c0 + 4 * tx;
            float4 base;
            if (panelrow) { base = make_float4(0.f, 0.f, 0.f, 0.f); }
            else          { base = *(const float4*)dst; }
            float4 v;
            v.x = base.x + acc[i][0];
            v.y = base.y + acc[i][1];
            v.z = base.z + acc[i][2];
            v.w = base.w + acc[i][3];
            if (p < NPAN - 1) {
                // stash next pass's R slice (rows of next panel, this col-tile)
                if ((rt >> 1) == p + 1 && (ct >> 1) != p + 1) {
                    const int slot = ct - (ct > 2 * p + 3 ? 2 : 0);
                    const int srow = rg - NB * (p + 1);
                    *(float4*)(rb + SB((p + 1) & 1, ag, slot) + srow * 60 + 4 * tx) = v;
                }
                *(float4*)dst = v;
            } else {
                // last pass: fold finalize  cov = c*I - c^2 * Sinv
                const int cg = c0 + 4 * tx;
                float4 o;
                o.x = ((rg == cg + 0) ? c : 0.f) - c2 * v.x;
                o.y = ((rg == cg + 1) ? c : 0.f) - c2 * v.y;
                o.z = ((rg == cg + 2) ? c : 0.f) - c2 * v.z;
                o.w = ((rg == cg + 3) ? c : 0.f) - c2 * v.w;
                *(float4*)dst = o;
            }
        }
    }
}

// ------- mean: m = obs - c*Sinv*d, via transformed C:  m = obs - d + (C^T d)/c
__global__ __launch_bounds__(384) void solve_mean_kernel(
    float* __restrict__ out, const float* __restrict__ mean_in,
    const float* __restrict__ obs, const float* __restrict__ rs,
    const int* __restrict__ init_f, const int* __restrict__ sel_f)
{
    const int ag = blockIdx.x;
    if (!(init_f[ag] && sel_f[ag])) return;
    const float* C = out + COV_OFF + (size_t)ag * D * D;
    __shared__ float dsh[D];
    const int t = threadIdx.x;
    if (t < D) dsh[t] = obs[ag * D + t] - mean_in[ag * D + gshift(t)];
    __syncthreads();
    if (t < D) {
        float dot = 0.0f;
        #pragma unroll 8
        for (int j = 0; j < D; ++j)
            dot = fmaf(C[(size_t)j * D + t], dsh[j], dot);   // coalesced col read
        const float c = rs[ag] + 1.0f;
        out[ag * D + t] = obs[ag * D + t] - dsh[t] + dot / c;
    }
}

extern "C" void kernel_launch(void* const* d_in, const int* in_sizes, int n_in,
                              void* d_out, int out_size, void* d_ws, size_t ws_size,
                              hipStream_t stream) {
    const float* mean_in     = (const float*)d_in[0];
    const float* P           = (const float*)d_in[1];
    const float* obs         = (const float*)d_in[2];
    const float* rs          = (const float*)d_in[3];
    const int*   initialized = (const int*)d_in[4];
    const int*   selected    = (const int*)d_in[5];
    float* out = (float*)d_out;
    float* rb  = (float*)d_ws;   // 2*64*4*7200 floats = 14.75 MB

    build_kernel<<<dim3(46, NAG), 384, 0, stream>>>(P, mean_in, obs, rs,
                                                    initialized, selected, out, rb);
    for (int p = 0; p < NPAN; ++p) {
        factor_kernel<<<NAG, 768, 0, stream>>>(out, rs, initialized, selected, rb, p);
        update_kernel<<<dim3(NAG, 4, 6), 256, 0, stream>>>(out, rs, initialized,
                                                           selected, rb, p);
    }
    solve_mean_kernel<<<NAG, 384, 0, stream>>>(out, mean_in, obs, rs, initialized, selected);
}

// Round 10
// 307.548 us; speedup vs baseline: 5.5755x; 1.2398x over previous
//
#include <hip/hip_runtime.h>

#define D 360
#define NAG 64
#define NB 60
#define NPAN 6
#define COV_OFF (NAG * D)
#define INIT_OFF (COV_OFF + NAG * D * D)
// ping-pong R stash in d_ws: [parity][agent][ct][60][60]
#define RBOFF(par, ag, ct) ((((par) * NAG + (ag)) * 6 + (ct)) * 3600)
// Binv stash (single buffer, reused each pass): [agent][60][60]
#define BVOFF(ag) (2764800 + (ag) * 3600)

__device__ __forceinline__ int gshift(int i) {
    return ((i % 60) < 58) ? (i + 2) : i;
}

// ------- build: S (upd) / final cov (others) + mean/flag + R0 stash ---------
__global__ __launch_bounds__(384) void build_kernel(
    const float* __restrict__ P, const float* __restrict__ mean_in,
    const float* __restrict__ obs, const float* __restrict__ rs,
    const int* __restrict__ init_f, const int* __restrict__ sel_f,
    float* __restrict__ out, float* __restrict__ rb)
{
    const int by = blockIdx.x, ag = blockIdx.y, t = threadIdx.x;
    const bool ini = init_f[ag] != 0, sel = sel_f[ag] != 0;
    const float c = rs[ag] + 1.0f;
    if (by == 45) {   // fused "small" block: mean passthrough/init + flag
        if (t < D) {
            float v = (sel && !ini) ? obs[ag * D + t] : mean_in[ag * D + t];
            out[ag * D + t] = v;     // upd agents overwritten by solve_mean
        }
        if (t == 0) out[INIT_OFF + ag] = (ini || sel) ? 1.0f : 0.0f;
        return;
    }
    if (t >= D) return;
    const float* Pa = P + (size_t)ag * D * D;
    float* cov = out + COV_OFF + (size_t)ag * D * D;
    const int j = t;
    if (sel && ini) {
        const int gj = gshift(j);
        #pragma unroll
        for (int s = 0; s < 8; ++s) {
            const int i = by * 8 + s;
            float v = Pa[(size_t)gshift(i) * D + gj];
            if (i == j) v += 1.0f + c;           // + process(1) + obs(c)
            cov[(size_t)i * D + j] = v;
            if (i < NB && j >= NB)               // stash R slices for pass 0
                rb[RBOFF(0, ag, j / NB) + i * NB + (j % NB)] = v;
        }
    } else if (sel) {
        #pragma unroll
        for (int s = 0; s < 8; ++s) {
            const int i = by * 8 + s;
            cov[(size_t)i * D + j] = Pa[(size_t)i * D + j] + ((i == j) ? c : 0.0f);
        }
    } else {
        #pragma unroll
        for (int s = 0; s < 8; ++s) {
            const int i = by * 8 + s;
            cov[(size_t)i * D + j] = Pa[(size_t)i * D + j];
        }
    }
}

// ---------------- 4x4 in-place GJ inverse (no pivoting; SPD blocks) ----------
__device__ __forceinline__ void inv4(float4& m0, float4& m1, float4& m2, float4& m3)
{
    float pv, f;
    pv = 1.0f / m0.x;
    m0.y *= pv; m0.z *= pv; m0.w *= pv; m0.x = pv;
    f = m1.x; m1.y = fmaf(-f, m0.y, m1.y); m1.z = fmaf(-f, m0.z, m1.z); m1.w = fmaf(-f, m0.w, m1.w); m1.x = -f * pv;
    f = m2.x; m2.y = fmaf(-f, m0.y, m2.y); m2.z = fmaf(-f, m0.z, m2.z); m2.w = fmaf(-f, m0.w, m2.w); m2.x = -f * pv;
    f = m3.x; m3.y = fmaf(-f, m0.y, m3.y); m3.z = fmaf(-f, m0.z, m3.z); m3.w = fmaf(-f, m0.w, m3.w); m3.x = -f * pv;
    pv = 1.0f / m1.y;
    m1.x *= pv; m1.z *= pv; m1.w *= pv; m1.y = pv;
    f = m0.y; m0.x = fmaf(-f, m1.x, m0.x); m0.z = fmaf(-f, m1.z, m0.z); m0.w = fmaf(-f, m1.w, m0.w); m0.y = -f * pv;
    f = m2.y; m2.x = fmaf(-f, m1.x, m2.x); m2.z = fmaf(-f, m1.z, m2.z); m2.w = fmaf(-f, m1.w, m2.w); m2.y = -f * pv;
    f = m3.y; m3.x = fmaf(-f, m1.x, m3.x); m3.z = fmaf(-f, m1.z, m3.z); m3.w = fmaf(-f, m1.w, m3.w); m3.y = -f * pv;
    pv = 1.0f / m2.z;
    m2.x *= pv; m2.y *= pv; m2.w *= pv; m2.z = pv;
    f = m0.z; m0.x = fmaf(-f, m2.x, m0.x); m0.y = fmaf(-f, m2.y, m0.y); m0.w = fmaf(-f, m2.w, m0.w); m0.z = -f * pv;
    f = m1.z; m1.x = fmaf(-f, m2.x, m1.x); m1.y = fmaf(-f, m2.y, m1.y); m1.w = fmaf(-f, m2.w, m1.w); m1.z = -f * pv;
    f = m3.z; m3.x = fmaf(-f, m2.x, m3.x); m3.y = fmaf(-f, m2.y, m3.y); m3.w = fmaf(-f, m2.w, m3.w); m3.z = -f * pv;
    pv = 1.0f / m3.w;
    m3.x *= pv; m3.y *= pv; m3.z *= pv; m3.w = pv;
    f = m0.w; m0.x = fmaf(-f, m3.x, m0.x); m0.y = fmaf(-f, m3.y, m0.y); m0.z = fmaf(-f, m3.z, m0.z); m0.w = -f * pv;
    f = m1.w; m1.x = fmaf(-f, m3.x, m1.x); m1.y = fmaf(-f, m3.y, m1.y); m1.z = fmaf(-f, m3.z, m1.z); m1.w = -f * pv;
    f = m2.w; m2.x = fmaf(-f, m3.x, m2.x); m2.y = fmaf(-f, m3.y, m2.y); m2.z = fmaf(-f, m3.z, m2.z); m2.w = -f * pv;
}

// ---- named-register slab: 15 float4 members, all access compile-time -------
struct Slab {
    float4 v0, v1, v2, v3, v4, v5, v6, v7, v8, v9, v10, v11, v12, v13, v14;
};
template<int I> __device__ __forceinline__ float4& AT(Slab& s) {
    if constexpr (I == 0) return s.v0;   else if constexpr (I == 1) return s.v1;
    else if constexpr (I == 2) return s.v2;  else if constexpr (I == 3) return s.v3;
    else if constexpr (I == 4) return s.v4;  else if constexpr (I == 5) return s.v5;
    else if constexpr (I == 6) return s.v6;  else if constexpr (I == 7) return s.v7;
    else if constexpr (I == 8) return s.v8;  else if constexpr (I == 9) return s.v9;
    else if constexpr (I == 10) return s.v10; else if constexpr (I == 11) return s.v11;
    else if constexpr (I == 12) return s.v12; else if constexpr (I == 13) return s.v13;
    else return s.v14;
}
template<int Q = 0> __device__ __forceinline__ void slab_load(Slab& s, const float* src) {
    if constexpr (Q < 15) { AT<Q>(s) = *(const float4*)(src + 4 * Q); slab_load<Q + 1>(s, src); }
}
template<int Q = 0> __device__ __forceinline__ void slab_store(Slab& s, float* dst) {
    if constexpr (Q < 15) { *(float4*)(dst + 4 * Q) = AT<Q>(s); slab_store<Q + 1>(s, dst); }
}
template<int Q = 0> __device__ __forceinline__ void slab_stage(Slab& s, float4 (&dst)[15]) {
    if constexpr (Q < 15) { dst[Q] = AT<Q>(s); slab_stage<Q + 1>(s, dst); }
}
template<int KB, int Q = 0> __device__ __forceinline__ void zero_except(Slab& s) {
    if constexpr (Q < 15) {
        if constexpr (Q != KB) AT<Q>(s) = make_float4(0.f, 0.f, 0.f, 0.f);
        zero_except<KB, Q + 1>(s);
    }
}
template<int KB, int Q = 0>
__device__ __forceinline__ void rank4(Slab& s, const float4 sc, const float4 (&pb)[4][15]) {
    if constexpr (Q < 15) {
        if constexpr (Q != KB) {
            const float4 p0 = pb[0][Q], p1 = pb[1][Q], p2 = pb[2][Q], p3 = pb[3][Q];
            float4& r = AT<Q>(s);
            r.x = fmaf(sc.x, p0.x, fmaf(sc.y, p1.x, fmaf(sc.z, p2.x, fmaf(sc.w, p3.x, r.x))));
            r.y = fmaf(sc.x, p0.y, fmaf(sc.y, p1.y, fmaf(sc.z, p2.y, fmaf(sc.w, p3.y, r.y))));
            r.z = fmaf(sc.x, p0.z, fmaf(sc.y, p1.z, fmaf(sc.z, p2.z, fmaf(sc.w, p3.z, r.z))));
            r.w = fmaf(sc.x, p0.w, fmaf(sc.y, p1.w, fmaf(sc.z, p2.w, fmaf(sc.w, p3.w, r.w))));
        }
        rank4<KB, Q + 1>(s, sc, pb);
    }
}

template<int KB>
__device__ __forceinline__ void gj_step(Slab& s, int r, int rel, float4 (&praw)[2][4][15])
{
    const int buf = KB & 1;
    float4 m0 = praw[buf][0][KB];
    float4 m1 = praw[buf][1][KB];
    float4 m2 = praw[buf][2][KB];
    float4 m3 = praw[buf][3][KB];
    inv4(m0, m1, m2, m3);
    if (r < D) {
        const bool is_piv = (rel >= 4 * KB) && (rel < 4 * KB + 4);
        float4 sc;
        if (is_piv) {
            const int i = rel - 4 * KB;
            sc = (i == 0) ? m0 : (i == 1) ? m1 : (i == 2) ? m2 : m3;
            zero_except<KB>(s);
        } else {
            const float4 fr = AT<KB>(s);
            sc.x = -(fr.x * m0.x + fr.y * m1.x + fr.z * m2.x + fr.w * m3.x);
            sc.y = -(fr.x * m0.y + fr.y * m1.y + fr.z * m2.y + fr.w * m3.y);
            sc.z = -(fr.x * m0.z + fr.y * m1.z + fr.z * m2.z + fr.w * m3.z);
            sc.w = -(fr.x * m0.w + fr.y * m1.w + fr.z * m2.w + fr.w * m3.w);
        }
        rank4<KB>(s, sc, praw[buf]);
        AT<KB>(s) = sc;
        if (KB < 14 && rel >= 4 * (KB + 1) && rel < 4 * (KB + 1) + 4) {
            slab_stage(s, praw[buf ^ 1][rel - 4 * (KB + 1)]);
        }
    }
    __syncthreads();
}

template<int KB> struct GJ {
    __device__ static __forceinline__ void run(Slab& s, int r, int rel,
                                               float4 (&praw)[2][4][15]) {
        gj_step<KB>(s, r, rel, praw);
        GJ<KB + 1>::run(s, r, rel, praw);
    }
};
template<> struct GJ<15> {
    __device__ static __forceinline__ void run(Slab&, int, int, float4 (&)[2][4][15]) {}
};

// ------- diag_inv: single-wave 60x60 in-register GJ inverse of B ------------
__global__ __launch_bounds__(64) void diag_inv_kernel(
    const float* __restrict__ out, const int* __restrict__ init_f,
    const int* __restrict__ sel_f, float* __restrict__ rb, int p)
{
    const int ag = blockIdx.x;
    if (!(init_f[ag] && sel_f[ag])) return;
    const float* M = out + COV_OFF + (size_t)ag * D * D;
    const int j0 = p * NB;
    const int lane = threadIdx.x;            // 0..63; rows 0..59 active
    const int r = (lane < NB) ? lane : 999;  // guard token for gj_step
    Slab s;
    if (lane < NB) slab_load(s, M + (size_t)(j0 + lane) * D + j0);
    __shared__ float4 praw[2][4][15];
    if (lane < 4) slab_stage(s, praw[0][lane]);
    __syncthreads();
    GJ<0>::run(s, r, lane, praw);
    if (lane < NB) slab_store(s, rb + BVOFF(ag) + lane * NB);
}

// ------- colpanel: M[rt-block, p] = (rt==p ? Binv : -C*Binv) ----------------
__device__ __forceinline__ void mm_row(const float4 a, const float4 b0, const float4 b1,
                                       const float4 b2, const float4 b3, float acc[4]) {
    acc[0] = fmaf(a.x, b0.x, fmaf(a.y, b1.x, fmaf(a.z, b2.x, fmaf(a.w, b3.x, acc[0]))));
    acc[1] = fmaf(a.x, b0.y, fmaf(a.y, b1.y, fmaf(a.z, b2.y, fmaf(a.w, b3.y, acc[1]))));
    acc[2] = fmaf(a.x, b0.z, fmaf(a.y, b1.z, fmaf(a.z, b2.z, fmaf(a.w, b3.z, acc[2]))));
    acc[3] = fmaf(a.x, b0.w, fmaf(a.y, b1.w, fmaf(a.z, b2.w, fmaf(a.w, b3.w, acc[3]))));
}

__global__ __launch_bounds__(256) void colpanel_kernel(
    float* __restrict__ out, const float* __restrict__ rs,
    const int* __restrict__ init_f, const int* __restrict__ sel_f,
    float* __restrict__ rb, int p)
{
    const int ag = blockIdx.x;
    if (!(init_f[ag] && sel_f[ag])) return;
    const int rt = blockIdx.y;               // 0..5
    float* M = out + COV_OFF + (size_t)ag * D * D;
    const int j0 = p * NB, r0 = rt * NB;
    const float c = rs[ag] + 1.0f;
    const float c2 = c * c;
    const bool ispnl = (rt == p);
    __shared__ float Bsh[NB][64];
    __shared__ float Csh[NB][64];
    const int t = threadIdx.x;
    for (int idx = t; idx < NB * 15; idx += 256) {
        const int k = idx / 15, q = idx % 15;
        *(float4*)&Bsh[k][4 * q] = *(const float4*)(rb + BVOFF(ag) + k * NB + 4 * q);
    }
    if (!ispnl) {
        for (int idx = t; idx < NB * 15; idx += 256) {
            const int i = idx / 15, q = idx % 15;
            *(float4*)&Csh[i][4 * q] = *(const float4*)(M + (size_t)(r0 + i) * D + j0 + 4 * q);
        }
    }
    __syncthreads();
    const int tx = t % 16, ty = t / 16;
    if (tx < 15 && ty < 15) {
        float acc[4][4];
        #pragma unroll
        for (int i = 0; i < 4; ++i)
            #pragma unroll
            for (int j = 0; j < 4; ++j) acc[i][j] = 0.0f;
        if (ispnl) {
            #pragma unroll
            for (int i = 0; i < 4; ++i)
                #pragma unroll
                for (int j = 0; j < 4; ++j) acc[i][j] = Bsh[4 * ty + i][4 * tx + j];
        } else {
            for (int kq = 0; kq < 15; ++kq) {
                float4 a0 = *(const float4*)&Csh[4 * ty + 0][4 * kq];
                float4 a1 = *(const float4*)&Csh[4 * ty + 1][4 * kq];
                float4 a2 = *(const float4*)&Csh[4 * ty + 2][4 * kq];
                float4 a3 = *(const float4*)&Csh[4 * ty + 3][4 * kq];
                float4 b0 = *(const float4*)&Bsh[4 * kq + 0][4 * tx];
                float4 b1 = *(const float4*)&Bsh[4 * kq + 1][4 * tx];
                float4 b2 = *(const float4*)&Bsh[4 * kq + 2][4 * tx];
                float4 b3 = *(const float4*)&Bsh[4 * kq + 3][4 * tx];
                mm_row(a0, b0, b1, b2, b3, acc[0]);
                mm_row(a1, b0, b1, b2, b3, acc[1]);
                mm_row(a2, b0, b1, b2, b3, acc[2]);
                mm_row(a3, b0, b1, b2, b3, acc[3]);
            }
            #pragma unroll
            for (int i = 0; i < 4; ++i)
                #pragma unroll
                for (int j = 0; j < 4; ++j) acc[i][j] = -acc[i][j];
        }
        #pragma unroll
        for (int i = 0; i < 4; ++i) {
            const int rg = r0 + 4 * ty + i;
            float4 v = make_float4(acc[i][0], acc[i][1], acc[i][2], acc[i][3]);
            float* dst = M + (size_t)rg * D + j0 + 4 * tx;
            if (p == NPAN - 1) {
                // last pass: panel cols are final -> fold cov = c*I - c^2 * Sinv
                const int cg = j0 + 4 * tx;
                float4 o;
                o.x = ((rg == cg + 0) ? c : 0.f) - c2 * v.x;
                o.y = ((rg == cg + 1) ? c : 0.f) - c2 * v.y;
                o.z = ((rg == cg + 2) ? c : 0.f) - c2 * v.z;
                o.w = ((rg == cg + 3) ? c : 0.f) - c2 * v.w;
                *(float4*)dst = o;
            } else {
                *(float4*)dst = v;
                // stash next pass's R slice for col-tile ct==p (rows of next panel)
                if (rt == p + 1)
                    *(float4*)(rb + RBOFF((p + 1) & 1, ag, p) + (rg - NB * (p + 1)) * NB + 4 * tx) = v;
            }
        }
    }
}

// -------- update: M[:,ct] = (rt==p?0:M) + F*R ; R from stash; stash next R ---
__global__ __launch_bounds__(256) void update_kernel(
    float* __restrict__ out, const float* __restrict__ rs,
    const int* __restrict__ init_f, const int* __restrict__ sel_f,
    float* __restrict__ rb, int p)
{
    const int ag = blockIdx.x;
    if (!(init_f[ag] && sel_f[ag])) return;
    const int ct = blockIdx.y + (blockIdx.y >= p ? 1 : 0);
    float* M = out + COV_OFF + (size_t)ag * D * D;
    const int j0 = p * NB, c0 = ct * NB;
    const float c = rs[ag] + 1.0f;
    const float c2 = c * c;
    __shared__ float R[NB][NB + 8];
    __shared__ float F[NB][NB + 8];
    const int t = threadIdx.x;
    {   // R from the race-free stash
        const float* rsrc = rb + RBOFF(p & 1, ag, ct);
        for (int idx = t; idx < NB * 15; idx += 256) {
            int k = idx / 15, qq = idx % 15;
            *(float4*)&R[k][4 * qq] = *(const float4*)(rsrc + k * NB + 4 * qq);
        }
    }
    const int tx = t % 16, ty = t / 16;
    for (int rr = 0; rr < 2; ++rr) {
        const int rt = (int)blockIdx.z * 2 + rr;
        const int r0 = rt * NB;
        __syncthreads();
        for (int idx = t; idx < NB * 15; idx += 256) {
            int rrw = idx / 15, qq = idx % 15;
            float4 v = *(const float4*)(M + (size_t)(r0 + rrw) * D + j0 + 4 * qq);
            if (p == NPAN - 1) {
                // colpanel wrote transformed panel: recover raw F
                const int rg = r0 + rrw, cg = j0 + 4 * qq;
                v.x = (((rg == cg + 0) ? c : 0.f) - v.x) / c2;
                v.y = (((rg == cg + 1) ? c : 0.f) - v.y) / c2;
                v.z = (((rg == cg + 2) ? c : 0.f) - v.z) / c2;
                v.w = (((rg == cg + 3) ? c : 0.f) - v.w) / c2;
            }
            *(float4*)&F[rrw][4 * qq] = v;
        }
        __syncthreads();
        if (tx < 15 && ty < 15) {
            float acc[4][4];
            #pragma unroll
            for (int i = 0; i < 4; ++i)
                #pragma unroll
                for (int j = 0; j < 4; ++j) acc[i][j] = 0.0f;
            for (int kq = 0; kq < 15; ++kq) {
                float4 a0 = *(const float4*)&F[4 * ty + 0][4 * kq];
                float4 a1 = *(const float4*)&F[4 * ty + 1][4 * kq];
                float4 a2 = *(const float4*)&F[4 * ty + 2][4 * kq];
                float4 a3 = *(const float4*)&F[4 * ty + 3][4 * kq];
                float4 b0 = *(const float4*)&R[4 * kq + 0][4 * tx];
                float4 b1 = *(const float4*)&R[4 * kq + 1][4 * tx];
                float4 b2 = *(const float4*)&R[4 * kq + 2][4 * tx];
                float4 b3 = *(const float4*)&R[4 * kq + 3][4 * tx];
                mm_row(a0, b0, b1, b2, b3, acc[0]);
                mm_row(a1, b0, b1, b2, b3, acc[1]);
                mm_row(a2, b0, b1, b2, b3, acc[2]);
                mm_row(a3, b0, b1, b2, b3, acc[3]);
            }
            #pragma unroll
            for (int i = 0; i < 4; ++i) {
                const int rg = r0 + 4 * ty + i;
                float* dst = M + (size_t)rg * D + c0 + 4 * tx;
                float4 base;
                if (rt == p) { base = make_float4(0.f, 0.f, 0.f, 0.f); }
                else         { base = *(const float4*)dst; }
                float4 v;
                v.x = base.x + acc[i][0];
                v.y = base.y + acc[i][1];
                v.z = base.z + acc[i][2];
                v.w = base.w + acc[i][3];
                if (p < NPAN - 1) {
                    // stash next pass's R slice (rows of next panel, this col-tile)
                    if (rt == p + 1 && ct != p + 1) {
                        float* rdst = rb + RBOFF((p + 1) & 1, ag, ct) + (4 * ty + i) * NB + 4 * tx;
                        *(float4*)rdst = v;
                    }
                    *(float4*)dst = v;
                } else {
                    // last pass: fold finalize  cov = c*I - c^2 * Sinv
                    const int cg = c0 + 4 * tx;
                    float4 o;
                    o.x = ((rg == cg + 0) ? c : 0.f) - c2 * v.x;
                    o.y = ((rg == cg + 1) ? c : 0.f) - c2 * v.y;
                    o.z = ((rg == cg + 2) ? c : 0.f) - c2 * v.z;
                    o.w = ((rg == cg + 3) ? c : 0.f) - c2 * v.w;
                    *(float4*)dst = o;
                }
            }
        }
    }
}

// ------- mean: m = obs - c*Sinv*d, via transformed C:  m = obs - d + (C^T d)/c
__global__ __launch_bounds__(384) void solve_mean_kernel(
    float* __restrict__ out, const float* __restrict__ mean_in,
    const float* __restrict__ obs, const float* __restrict__ rs,
    const int* __restrict__ init_f, const int* __restrict__ sel_f)
{
    const int ag = blockIdx.x;
    if (!(init_f[ag] && sel_f[ag])) return;
    const float* C = out + COV_OFF + (size_t)ag * D * D;
    __shared__ float dsh[D];
    const int t = threadIdx.x;
    if (t < D) dsh[t] = obs[ag * D + t] - mean_in[ag * D + gshift(t)];
    __syncthreads();
    if (t < D) {
        float dot = 0.0f;
        #pragma unroll 8
        for (int j = 0; j < D; ++j)
            dot = fmaf(C[(size_t)j * D + t], dsh[j], dot);   // coalesced col read
        const float c = rs[ag] + 1.0f;
        out[ag * D + t] = obs[ag * D + t] - dsh[t] + dot / c;
    }
}

extern "C" void kernel_launch(void* const* d_in, const int* in_sizes, int n_in,
                              void* d_out, int out_size, void* d_ws, size_t ws_size,
                              hipStream_t stream) {
    const float* mean_in     = (const float*)d_in[0];
    const float* P           = (const float*)d_in[1];
    const float* obs         = (const float*)d_in[2];
    const float* rs          = (const float*)d_in[3];
    const int*   initialized = (const int*)d_in[4];
    const int*   selected    = (const int*)d_in[5];
    float* out = (float*)d_out;
    float* rb  = (float*)d_ws;   // R stash 11.06 MB + Binv stash 0.92 MB

    build_kernel<<<dim3(46, NAG), 384, 0, stream>>>(P, mean_in, obs, rs,
                                                    initialized, selected, out, rb);
    for (int p = 0; p < NPAN; ++p) {
        diag_inv_kernel<<<NAG, 64, 0, stream>>>(out, initialized, selected, rb, p);
        colpanel_kernel<<<dim3(NAG, 6), 256, 0, stream>>>(out, rs, initialized,
                                                          selected, rb, p);
        update_kernel<<<dim3(NAG, NPAN - 1, 3), 256, 0, stream>>>(out, rs, initialized,
                                                                  selected, rb, p);
    }
    solve_mean_kernel<<<NAG, 384, 0, stream>>>(out, mean_in, obs, rs, initialized, selected);
}